// Round 4
// baseline (451.353 us; speedup 1.0000x reference)
//
#include <hip/hip_runtime.h>

#define DD 128

constexpr int cN1 = 50000, cN2 = 10000;

// ---------------------------------------------------------------------------
// Fused CSR step 1 (both graphs): histogram of dst + per-edge rank.
// ---------------------------------------------------------------------------
__global__ __launch_bounds__(256) void hist_rank2_kernel(
    const int* __restrict__ d1, int E1, int* __restrict__ cnt1, int* __restrict__ rank1,
    const int* __restrict__ d2, int E2, int* __restrict__ cnt2, int* __restrict__ rank2) {
  int e = blockIdx.x * 256 + threadIdx.x;
  if (e < E1) {
    rank1[e] = atomicAdd(&cnt1[d1[e]], 1);
  } else {
    e -= E1;
    if (e < E2) rank2[e] = atomicAdd(&cnt2[d2[e]], 1);
  }
}

// ---------------------------------------------------------------------------
// Fused CSR step 2 (both graphs): single-block exclusive scan per graph.
// Block 0 -> graph 1 (n1 elts), block 1 -> graph 2. 1024 threads, each owns a
// contiguous chunk; LDS Hillis-Steele over the 1024 partials. Totals are the
// known edge counts, no extra pass.
// ---------------------------------------------------------------------------
__global__ __launch_bounds__(1024) void scan_both_kernel(
    const int* __restrict__ cnt1, int n1, int* __restrict__ ofs1, int total1,
    const int* __restrict__ cnt2, int n2, int* __restrict__ ofs2, int total2) {
  const int* cnt; int n; int* ofs; int total;
  if (blockIdx.x == 0) { cnt = cnt1; n = n1; ofs = ofs1; total = total1; }
  else                 { cnt = cnt2; n = n2; ofs = ofs2; total = total2; }

  __shared__ int part[1024];
  int t = threadIdx.x;
  int chunk = (n + 1023) >> 10;
  int lo = t * chunk;
  int hi = lo + chunk; if (hi > n) hi = n;

  int s = 0;
  for (int i = lo; i < hi; ++i) s += cnt[i];
  part[t] = s;
  __syncthreads();
  for (int d = 1; d < 1024; d <<= 1) {
    int v = (t >= d) ? part[t - d] : 0;
    __syncthreads();
    part[t] += v;
    __syncthreads();
  }
  int run = (t == 0) ? 0 : part[t - 1];
  for (int i = lo; i < hi; ++i) {
    int c = cnt[i];
    ofs[i] = run;
    run += c;
  }
  if (t == 0) ofs[n] = total;
}

// ---------------------------------------------------------------------------
// Fused CSR step 3 (both graphs): scatter (src, w) pairs into dst-sorted
// order. No atomics: pos = ofs[dst] + rank.
// ---------------------------------------------------------------------------
__global__ __launch_bounds__(256) void scatter2_kernel(
    const int* __restrict__ s1, const int* __restrict__ d1, const float* __restrict__ w1,
    const int* __restrict__ rank1, const int* __restrict__ ofs1, int E1,
    unsigned long long* __restrict__ sorted1,
    const int* __restrict__ s2, const int* __restrict__ d2, const float* __restrict__ w2,
    const int* __restrict__ rank2, const int* __restrict__ ofs2, int E2,
    unsigned long long* __restrict__ sorted2) {
  int e = blockIdx.x * 256 + threadIdx.x;
  if (e < E1) {
    int pos = ofs1[d1[e]] + rank1[e];
    unsigned long long pk =
        (unsigned long long)(unsigned int)s1[e] |
        ((unsigned long long)__float_as_uint(w1[e]) << 32);
    __builtin_nontemporal_store(pk, sorted1 + pos);
  } else {
    e -= E1;
    if (e < E2) {
      int pos = ofs2[d2[e]] + rank2[e];
      unsigned long long pk =
          (unsigned long long)(unsigned int)s2[e] |
          ((unsigned long long)__float_as_uint(w2[e]) << 32);
      __builtin_nontemporal_store(pk, sorted2 + pos);
    }
  }
}

// ---------------------------------------------------------------------------
// Gather-side SpMM: one wave per dst row, lane owns float2 (64*8B = 512B row).
// ---------------------------------------------------------------------------
#define GATHER(P, VX, VY)                                                        \
  {                                                                              \
    int s_ = (int)(unsigned int)(P);                                             \
    const float2* pr_ = reinterpret_cast<const float2*>(h_in + (size_t)s_ * DD); \
    float2 v_ = pr_[lane];                                                       \
    float w_ = __uint_as_float((unsigned int)((P) >> 32));                       \
    VX += v_.x * w_;                                                             \
    VY += v_.y * w_;                                                             \
  }

__global__ __launch_bounds__(256) void spmm_csr_kernel(
    const float* __restrict__ h_in,
    const int* __restrict__ ofs,
    const unsigned long long* __restrict__ sorted,
    float* __restrict__ h_out,
    int nrows) {
  int wave = (blockIdx.x * 256 + threadIdx.x) >> 6;
  int lane = threadIdx.x & 63;
  if (wave >= nrows) return;

  int lo = ofs[wave];
  int hi = ofs[wave + 1];

  float accx = 0.f, accy = 0.f;
  float ax1 = 0.f, ay1 = 0.f;
  int j = lo;
  for (; j + 8 <= hi; j += 8) {
    unsigned long long p0 = __builtin_nontemporal_load(sorted + j);
    unsigned long long p1 = __builtin_nontemporal_load(sorted + j + 1);
    unsigned long long p2 = __builtin_nontemporal_load(sorted + j + 2);
    unsigned long long p3 = __builtin_nontemporal_load(sorted + j + 3);
    unsigned long long p4 = __builtin_nontemporal_load(sorted + j + 4);
    unsigned long long p5 = __builtin_nontemporal_load(sorted + j + 5);
    unsigned long long p6 = __builtin_nontemporal_load(sorted + j + 6);
    unsigned long long p7 = __builtin_nontemporal_load(sorted + j + 7);
    GATHER(p0, accx, accy) GATHER(p1, ax1, ay1)
    GATHER(p2, accx, accy) GATHER(p3, ax1, ay1)
    GATHER(p4, accx, accy) GATHER(p5, ax1, ay1)
    GATHER(p6, accx, accy) GATHER(p7, ax1, ay1)
  }
  for (; j + 2 <= hi; j += 2) {
    unsigned long long p0 = __builtin_nontemporal_load(sorted + j);
    unsigned long long p1 = __builtin_nontemporal_load(sorted + j + 1);
    GATHER(p0, accx, accy) GATHER(p1, ax1, ay1)
  }
  if (j < hi) {
    unsigned long long p0 = __builtin_nontemporal_load(sorted + j);
    GATHER(p0, accx, accy)
  }

  float2 o;
  o.x = accx + ax1;
  o.y = accy + ay1;
  reinterpret_cast<float2*>(h_out + (size_t)wave * DD)[lane] = o;
}

// ---------------------------------------------------------------------------
// SpMM block 2 fused with the linear epilogue:
//   h2row = sum over edges, then out[row,c] = b[c] + dot(h2row, W[c,:]).
// Wave computes h2row (float2/lane), stages it in per-wave LDS (wave-
// synchronous, no barrier), then each lane computes columns {lane, lane+64}.
// ---------------------------------------------------------------------------
__global__ __launch_bounds__(256) void spmm_linear_kernel(
    const float* __restrict__ h_in,
    const int* __restrict__ ofs,
    const unsigned long long* __restrict__ sorted,
    const float* __restrict__ W,
    const float* __restrict__ b,
    float* __restrict__ out,
    int nrows) {
  __shared__ float hrow[4][DD];
  int wid  = threadIdx.x >> 6;
  int lane = threadIdx.x & 63;
  int row  = blockIdx.x * 4 + wid;
  if (row >= nrows) return;

  int lo = ofs[row];
  int hi = ofs[row + 1];

  float accx = 0.f, accy = 0.f;
  float ax1 = 0.f, ay1 = 0.f;
  int j = lo;
  for (; j + 4 <= hi; j += 4) {
    unsigned long long p0 = __builtin_nontemporal_load(sorted + j);
    unsigned long long p1 = __builtin_nontemporal_load(sorted + j + 1);
    unsigned long long p2 = __builtin_nontemporal_load(sorted + j + 2);
    unsigned long long p3 = __builtin_nontemporal_load(sorted + j + 3);
    GATHER(p0, accx, accy) GATHER(p1, ax1, ay1)
    GATHER(p2, accx, accy) GATHER(p3, ax1, ay1)
  }
  for (; j < hi; ++j) {
    unsigned long long p0 = __builtin_nontemporal_load(sorted + j);
    GATHER(p0, accx, accy)
  }

  hrow[wid][2 * lane]     = accx + ax1;
  hrow[wid][2 * lane + 1] = accy + ay1;
  // same wave wrote hrow[wid] -> wave-synchronous, no barrier needed

  float a0 = b[lane];
  float a1 = b[lane + 64];
  const float* w0 = W + (size_t)lane * DD;
  const float* w1 = W + (size_t)(lane + 64) * DD;
  const float* hr = hrow[wid];
#pragma unroll 8
  for (int d = 0; d < DD; ++d) {
    float h = hr[d];           // LDS broadcast (same addr across lanes)
    a0 += h * w0[d];
    a1 += h * w1[d];
  }
  out[(size_t)row * DD + lane]      = a0;
  out[(size_t)row * DD + lane + 64] = a1;
}

#undef GATHER

static inline size_t align256(size_t x) { return (x + 255) & ~size_t(255); }

extern "C" void kernel_launch(void* const* d_in, const int* in_sizes, int n_in,
                              void* d_out, int out_size, void* d_ws, size_t ws_size,
                              hipStream_t stream) {
  const float* x   = (const float*)d_in[0];
  const float* ew1 = (const float*)d_in[1];
  const float* ew2 = (const float*)d_in[2];
  const float* W   = (const float*)d_in[3];
  const float* b   = (const float*)d_in[4];
  const int* e1_src = (const int*)d_in[5];
  const int* e1_dst = (const int*)d_in[6];
  const int* e2_src = (const int*)d_in[7];
  const int* e2_dst = (const int*)d_in[8];
  float* out = (float*)d_out;

  int E1 = in_sizes[1];
  int E2 = in_sizes[2];

  // ---- workspace layout ----
  char* p = (char*)d_ws;
  float* h1 = (float*)p;                  p += align256((size_t)cN1 * DD * 4);
  int* cnt1 = (int*)p;                    // cnt1+cnt2 contiguous: one memset
  int* cnt2 = cnt1 + cN1;                 p += align256((size_t)(cN1 + cN2) * 4);
  int* ofs1 = (int*)p;                    p += align256((size_t)(cN1 + 1) * 4);
  int* ofs2 = (int*)p;                    p += align256((size_t)(cN2 + 1) * 4);
  int* rank1 = (int*)p;                   p += align256((size_t)E1 * 4);
  int* rank2 = (int*)p;                   p += align256((size_t)E2 * 4);
  unsigned long long* sorted1 = (unsigned long long*)p;  p += align256((size_t)E1 * 8);
  unsigned long long* sorted2 = (unsigned long long*)p;  p += align256((size_t)E2 * 8);

  // 1) zero both histograms in one memset
  hipMemsetAsync(cnt1, 0, (size_t)(cN1 + cN2) * 4, stream);

  // 2) fused histogram + rank for both graphs
  {
    int total = E1 + E2;
    hist_rank2_kernel<<<(total + 255) / 256, 256, 0, stream>>>(
        e1_dst, E1, cnt1, rank1, e2_dst, E2, cnt2, rank2);
  }

  // 3) both scans in one launch (block 0 -> graph1, block 1 -> graph2)
  scan_both_kernel<<<2, 1024, 0, stream>>>(cnt1, cN1, ofs1, E1,
                                           cnt2, cN2, ofs2, E2);

  // 4) fused scatter for both graphs
  {
    int total = E1 + E2;
    scatter2_kernel<<<(total + 255) / 256, 256, 0, stream>>>(
        e1_src, e1_dst, ew1, rank1, ofs1, E1, sorted1,
        e2_src, e2_dst, ew2, rank2, ofs2, E2, sorted2);
  }

  // 5) SpMM block 1: x -> h1
  spmm_csr_kernel<<<(cN1 + 3) / 4, 256, 0, stream>>>(x, ofs1, sorted1, h1, cN1);

  // 6) SpMM block 2 + linear fused: h1 -> out
  {
    int nrows = out_size / DD;  // N2
    spmm_linear_kernel<<<(nrows + 3) / 4, 256, 0, stream>>>(
        h1, ofs2, sorted2, W, b, out, nrows);
  }
}

// Round 5
// 342.823 us; speedup vs baseline: 1.3166x; 1.3166x over previous
//
#include <hip/hip_runtime.h>

#define DD 128

constexpr int cN1 = 50000, cN2 = 10000;

// ---------------------------------------------------------------------------
// CSR step 1 (both graphs fused): histogram of dst + per-edge rank.
// ---------------------------------------------------------------------------
__global__ __launch_bounds__(256) void hist_rank2_kernel(
    const int* __restrict__ d1, int E1, int* __restrict__ cnt1, int* __restrict__ rank1,
    const int* __restrict__ d2, int E2, int* __restrict__ cnt2, int* __restrict__ rank2) {
  int e = blockIdx.x * 256 + threadIdx.x;
  if (e < E1) {
    rank1[e] = atomicAdd(&cnt1[d1[e]], 1);
  } else {
    e -= E1;
    if (e < E2) rank2[e] = atomicAdd(&cnt2[d2[e]], 1);
  }
}

// ---------------------------------------------------------------------------
// CSR step 2a (both graphs fused): per-1024-chunk exclusive scan -> ofs,
// chunk totals -> bsum. Blocks [0,nb1) -> graph 1, [nb1, nb1+nb2) -> graph 2.
// ---------------------------------------------------------------------------
__global__ __launch_bounds__(256) void scan_blk2_kernel(
    const int* __restrict__ cnt1, int n1, int* __restrict__ ofs1, int* __restrict__ bsum1, int nb1,
    const int* __restrict__ cnt2, int n2, int* __restrict__ ofs2, int* __restrict__ bsum2) {
  const int* cnt; int n; int* ofs; int* bsum; int lb;
  if ((int)blockIdx.x < nb1) { cnt = cnt1; n = n1; ofs = ofs1; bsum = bsum1; lb = blockIdx.x; }
  else                       { cnt = cnt2; n = n2; ofs = ofs2; bsum = bsum2; lb = blockIdx.x - nb1; }

  __shared__ int tsum[256];
  int t = threadIdx.x;
  int base = lb * 1024 + t * 4;
  int v0 = (base     < n) ? cnt[base]     : 0;
  int v1 = (base + 1 < n) ? cnt[base + 1] : 0;
  int v2 = (base + 2 < n) ? cnt[base + 2] : 0;
  int v3 = (base + 3 < n) ? cnt[base + 3] : 0;
  tsum[t] = v0 + v1 + v2 + v3;
  __syncthreads();
  for (int d = 1; d < 256; d <<= 1) {
    int x = (t >= d) ? tsum[t - d] : 0;
    __syncthreads();
    tsum[t] += x;
    __syncthreads();
  }
  int ex = (t == 0) ? 0 : tsum[t - 1];
  if (base     < n) ofs[base]     = ex;
  if (base + 1 < n) ofs[base + 1] = ex + v0;
  if (base + 2 < n) ofs[base + 2] = ex + v0 + v1;
  if (base + 3 < n) ofs[base + 3] = ex + v0 + v1 + v2;
  if (t == 255) bsum[lb] = tsum[255];
}

// ---------------------------------------------------------------------------
// CSR step 2b (both graphs fused, 1 block / 2 waves): wave-scan of chunk sums
// (nb <= 64 each), bsum -> exclusive; write grand totals to ofs[n].
// ---------------------------------------------------------------------------
__global__ __launch_bounds__(128) void scan_bsum2_kernel(
    int* __restrict__ bsum1, int nb1, int* __restrict__ ofs1, int n1, int total1,
    int* __restrict__ bsum2, int nb2, int* __restrict__ ofs2, int n2, int total2) {
  int w = threadIdx.x >> 6;
  int lane = threadIdx.x & 63;
  int* bsum = w ? bsum2 : bsum1;
  int nb    = w ? nb2   : nb1;
  int orig = (lane < nb) ? bsum[lane] : 0;
  int v = orig;
  for (int d = 1; d < 64; d <<= 1) {
    int u = __shfl_up(v, d);
    if (lane >= d) v += u;
  }
  if (lane < nb) bsum[lane] = v - orig;   // exclusive
  if (lane == 0) {
    if (w) ofs2[n2] = total2; else ofs1[n1] = total1;
  }
}

// ---------------------------------------------------------------------------
// CSR step 2c (both graphs fused): add chunk base offsets in place.
// ---------------------------------------------------------------------------
__global__ __launch_bounds__(256) void scan_add2_kernel(
    int* __restrict__ ofs1, int n1, const int* __restrict__ bsum1, int nblk1,
    int* __restrict__ ofs2, int n2, const int* __restrict__ bsum2) {
  int blk = blockIdx.x;
  int t = threadIdx.x;
  if (blk < nblk1) {
    int i = blk * 256 + t;
    if (i < n1) ofs1[i] += bsum1[i >> 10];
  } else {
    int i = (blk - nblk1) * 256 + t;
    if (i < n2) ofs2[i] += bsum2[i >> 10];
  }
}

// ---------------------------------------------------------------------------
// CSR step 3 (both graphs fused): scatter (src, w) pairs into dst-sorted
// order. No atomics: pos = ofs[dst] + rank.
// ---------------------------------------------------------------------------
__global__ __launch_bounds__(256) void scatter2_kernel(
    const int* __restrict__ s1, const int* __restrict__ d1, const float* __restrict__ w1,
    const int* __restrict__ rank1, const int* __restrict__ ofs1, int E1,
    unsigned long long* __restrict__ sorted1,
    const int* __restrict__ s2, const int* __restrict__ d2, const float* __restrict__ w2,
    const int* __restrict__ rank2, const int* __restrict__ ofs2, int E2,
    unsigned long long* __restrict__ sorted2) {
  int e = blockIdx.x * 256 + threadIdx.x;
  if (e < E1) {
    int pos = ofs1[d1[e]] + rank1[e];
    unsigned long long pk =
        (unsigned long long)(unsigned int)s1[e] |
        ((unsigned long long)__float_as_uint(w1[e]) << 32);
    __builtin_nontemporal_store(pk, sorted1 + pos);
  } else {
    e -= E1;
    if (e < E2) {
      int pos = ofs2[d2[e]] + rank2[e];
      unsigned long long pk =
          (unsigned long long)(unsigned int)s2[e] |
          ((unsigned long long)__float_as_uint(w2[e]) << 32);
      __builtin_nontemporal_store(pk, sorted2 + pos);
    }
  }
}

// ---------------------------------------------------------------------------
// Transpose W (128x128): WT[d][c] = W[c][d]. One-time 64 KB shuffle.
// ---------------------------------------------------------------------------
__global__ __launch_bounds__(256) void wt_kernel(
    const float* __restrict__ W, float* __restrict__ WT) {
  int idx = blockIdx.x * 256 + threadIdx.x;  // 64 blocks * 256 = 16384
  int c = idx >> 7;
  int d = idx & 127;
  WT[d * DD + c] = W[idx];
}

// ---------------------------------------------------------------------------
// Gather-side SpMM: one wave per dst row, lane owns float2 (64*8B = 512B row).
// ---------------------------------------------------------------------------
#define GATHER(P, VX, VY)                                                        \
  {                                                                              \
    int s_ = (int)(unsigned int)(P);                                             \
    const float2* pr_ = reinterpret_cast<const float2*>(h_in + (size_t)s_ * DD); \
    float2 v_ = pr_[lane];                                                       \
    float w_ = __uint_as_float((unsigned int)((P) >> 32));                       \
    VX += v_.x * w_;                                                             \
    VY += v_.y * w_;                                                             \
  }

__global__ __launch_bounds__(256) void spmm_csr_kernel(
    const float* __restrict__ h_in,
    const int* __restrict__ ofs,
    const unsigned long long* __restrict__ sorted,
    float* __restrict__ h_out,
    int nrows) {
  int wave = (blockIdx.x * 256 + threadIdx.x) >> 6;
  int lane = threadIdx.x & 63;
  if (wave >= nrows) return;

  int lo = ofs[wave];
  int hi = ofs[wave + 1];

  float accx = 0.f, accy = 0.f;
  float ax1 = 0.f, ay1 = 0.f;
  int j = lo;
  for (; j + 8 <= hi; j += 8) {
    unsigned long long p0 = __builtin_nontemporal_load(sorted + j);
    unsigned long long p1 = __builtin_nontemporal_load(sorted + j + 1);
    unsigned long long p2 = __builtin_nontemporal_load(sorted + j + 2);
    unsigned long long p3 = __builtin_nontemporal_load(sorted + j + 3);
    unsigned long long p4 = __builtin_nontemporal_load(sorted + j + 4);
    unsigned long long p5 = __builtin_nontemporal_load(sorted + j + 5);
    unsigned long long p6 = __builtin_nontemporal_load(sorted + j + 6);
    unsigned long long p7 = __builtin_nontemporal_load(sorted + j + 7);
    GATHER(p0, accx, accy) GATHER(p1, ax1, ay1)
    GATHER(p2, accx, accy) GATHER(p3, ax1, ay1)
    GATHER(p4, accx, accy) GATHER(p5, ax1, ay1)
    GATHER(p6, accx, accy) GATHER(p7, ax1, ay1)
  }
  for (; j + 2 <= hi; j += 2) {
    unsigned long long p0 = __builtin_nontemporal_load(sorted + j);
    unsigned long long p1 = __builtin_nontemporal_load(sorted + j + 1);
    GATHER(p0, accx, accy) GATHER(p1, ax1, ay1)
  }
  if (j < hi) {
    unsigned long long p0 = __builtin_nontemporal_load(sorted + j);
    GATHER(p0, accx, accy)
  }

  float2 o;
  o.x = accx + ax1;
  o.y = accy + ay1;
  reinterpret_cast<float2*>(h_out + (size_t)wave * DD)[lane] = o;
}

// ---------------------------------------------------------------------------
// SpMM block 2 fused with coalesced linear epilogue (uses WT = W^T):
//   h2row = sum over edges; out[row, c] = b[c] + sum_d h2row[d] * WT[d][c].
// Lane owns output cols {2*lane, 2*lane+1}: WT read is a coalesced float2,
// h2row[d] is an LDS broadcast.
// ---------------------------------------------------------------------------
__global__ __launch_bounds__(256) void spmm_linear_kernel(
    const float* __restrict__ h_in,
    const int* __restrict__ ofs,
    const unsigned long long* __restrict__ sorted,
    const float* __restrict__ WT,
    const float* __restrict__ b,
    float* __restrict__ out,
    int nrows) {
  __shared__ float hrow[4][DD];
  int wid  = threadIdx.x >> 6;
  int lane = threadIdx.x & 63;
  int row  = blockIdx.x * 4 + wid;
  if (row >= nrows) return;

  int lo = ofs[row];
  int hi = ofs[row + 1];

  float accx = 0.f, accy = 0.f;
  float ax1 = 0.f, ay1 = 0.f;
  int j = lo;
  for (; j + 4 <= hi; j += 4) {
    unsigned long long p0 = __builtin_nontemporal_load(sorted + j);
    unsigned long long p1 = __builtin_nontemporal_load(sorted + j + 1);
    unsigned long long p2 = __builtin_nontemporal_load(sorted + j + 2);
    unsigned long long p3 = __builtin_nontemporal_load(sorted + j + 3);
    GATHER(p0, accx, accy) GATHER(p1, ax1, ay1)
    GATHER(p2, accx, accy) GATHER(p3, ax1, ay1)
  }
  for (; j < hi; ++j) {
    unsigned long long p0 = __builtin_nontemporal_load(sorted + j);
    GATHER(p0, accx, accy)
  }

  hrow[wid][2 * lane]     = accx + ax1;
  hrow[wid][2 * lane + 1] = accy + ay1;
  // same wave wrote hrow[wid] -> wave-synchronous (worked R4; DS ops in-order)

  const float2* bp = reinterpret_cast<const float2*>(b);
  float2 bb = bp[lane];
  float a0 = bb.x;
  float a1 = bb.y;
  const float* hr = hrow[wid];
#pragma unroll 8
  for (int d = 0; d < DD; ++d) {
    float h = hr[d];  // LDS broadcast
    float2 w = *reinterpret_cast<const float2*>(WT + (size_t)d * DD + 2 * lane);
    a0 += h * w.x;
    a1 += h * w.y;
  }
  float2 o;
  o.x = a0;
  o.y = a1;
  reinterpret_cast<float2*>(out + (size_t)row * DD)[lane] = o;
}

#undef GATHER

static inline size_t align256(size_t x) { return (x + 255) & ~size_t(255); }

extern "C" void kernel_launch(void* const* d_in, const int* in_sizes, int n_in,
                              void* d_out, int out_size, void* d_ws, size_t ws_size,
                              hipStream_t stream) {
  const float* x   = (const float*)d_in[0];
  const float* ew1 = (const float*)d_in[1];
  const float* ew2 = (const float*)d_in[2];
  const float* W   = (const float*)d_in[3];
  const float* b   = (const float*)d_in[4];
  const int* e1_src = (const int*)d_in[5];
  const int* e1_dst = (const int*)d_in[6];
  const int* e2_src = (const int*)d_in[7];
  const int* e2_dst = (const int*)d_in[8];
  float* out = (float*)d_out;

  int E1 = in_sizes[1];
  int E2 = in_sizes[2];

  int nb1 = (cN1 + 1023) / 1024;  // 49
  int nb2 = (cN2 + 1023) / 1024;  // 10

  // ---- workspace layout ----
  char* p = (char*)d_ws;
  float* h1 = (float*)p;                  p += align256((size_t)cN1 * DD * 4);
  float* WT = (float*)p;                  p += align256((size_t)DD * DD * 4);
  int* cnt1 = (int*)p;                    // cnt1+cnt2 contiguous: one memset
  int* cnt2 = cnt1 + cN1;                 p += align256((size_t)(cN1 + cN2) * 4);
  int* ofs1 = (int*)p;                    p += align256((size_t)(cN1 + 1) * 4);
  int* ofs2 = (int*)p;                    p += align256((size_t)(cN2 + 1) * 4);
  int* bsum1 = (int*)p;                   p += align256(64 * 4);
  int* bsum2 = (int*)p;                   p += align256(64 * 4);
  int* rank1 = (int*)p;                   p += align256((size_t)E1 * 4);
  int* rank2 = (int*)p;                   p += align256((size_t)E2 * 4);
  unsigned long long* sorted1 = (unsigned long long*)p;  p += align256((size_t)E1 * 8);
  unsigned long long* sorted2 = (unsigned long long*)p;  p += align256((size_t)E2 * 8);

  // 1) zero both histograms in one memset
  hipMemsetAsync(cnt1, 0, (size_t)(cN1 + cN2) * 4, stream);

  // 2) transpose W (independent; overlaps nothing but is ~2 us)
  wt_kernel<<<64, 256, 0, stream>>>(W, WT);

  // 3) fused histogram + rank for both graphs
  {
    int total = E1 + E2;
    hist_rank2_kernel<<<(total + 255) / 256, 256, 0, stream>>>(
        e1_dst, E1, cnt1, rank1, e2_dst, E2, cnt2, rank2);
  }

  // 4) parallel scan: 2a (59 blocks) -> 2b (1 block) -> 2c (236 blocks)
  scan_blk2_kernel<<<nb1 + nb2, 256, 0, stream>>>(cnt1, cN1, ofs1, bsum1, nb1,
                                                  cnt2, cN2, ofs2, bsum2);
  scan_bsum2_kernel<<<1, 128, 0, stream>>>(bsum1, nb1, ofs1, cN1, E1,
                                           bsum2, nb2, ofs2, cN2, E2);
  {
    int nblk1 = (cN1 + 255) / 256;
    int nblk2 = (cN2 + 255) / 256;
    scan_add2_kernel<<<nblk1 + nblk2, 256, 0, stream>>>(ofs1, cN1, bsum1, nblk1,
                                                        ofs2, cN2, bsum2);
  }

  // 5) fused scatter for both graphs
  {
    int total = E1 + E2;
    scatter2_kernel<<<(total + 255) / 256, 256, 0, stream>>>(
        e1_src, e1_dst, ew1, rank1, ofs1, E1, sorted1,
        e2_src, e2_dst, ew2, rank2, ofs2, E2, sorted2);
  }

  // 6) SpMM block 1: x -> h1
  spmm_csr_kernel<<<(cN1 + 3) / 4, 256, 0, stream>>>(x, ofs1, sorted1, h1, cN1);

  // 7) SpMM block 2 + coalesced linear: h1 -> out
  {
    int nrows = out_size / DD;  // N2
    spmm_linear_kernel<<<(nrows + 3) / 4, 256, 0, stream>>>(
        h1, ofs2, sorted2, WT, b, out, nrows);
  }
}

// Round 6
// 292.138 us; speedup vs baseline: 1.5450x; 1.1735x over previous
//
#include <hip/hip_runtime.h>

#define DD 128

constexpr int cN0 = 100000, cN1 = 50000, cN2 = 10000;

// ---------------------------------------------------------------------------
// bf16 helpers (packed 2x bf16 in a u32; lo 16 bits = even col, hi = odd col)
// ---------------------------------------------------------------------------
__device__ __forceinline__ float bf_lo(unsigned int u) {
  return __uint_as_float(u << 16);
}
__device__ __forceinline__ float bf_hi(unsigned int u) {
  return __uint_as_float(u & 0xFFFF0000u);
}
__device__ __forceinline__ unsigned int pack_bf2(float a, float b) {
  unsigned int ua = __float_as_uint(a), ub = __float_as_uint(b);
  ua += 0x7FFFu + ((ua >> 16) & 1u);   // round-to-nearest-even
  ub += 0x7FFFu + ((ub >> 16) & 1u);
  return (ua >> 16) | (ub & 0xFFFF0000u);
}

// ---------------------------------------------------------------------------
// fp32 -> packed bf16 conversion, 8 floats / thread.
// ---------------------------------------------------------------------------
__global__ __launch_bounds__(256) void cvt_bf16_kernel(
    const float* __restrict__ in, unsigned int* __restrict__ outp, long long n8) {
  long long i = (long long)blockIdx.x * 256 + threadIdx.x;
  if (i >= n8) return;
  const float4* f4 = reinterpret_cast<const float4*>(in) + i * 2;
  float4 a = f4[0];
  float4 b = f4[1];
  uint4 o;
  o.x = pack_bf2(a.x, a.y);
  o.y = pack_bf2(a.z, a.w);
  o.z = pack_bf2(b.x, b.y);
  o.w = pack_bf2(b.z, b.w);
  reinterpret_cast<uint4*>(outp)[i] = o;
}

// ---------------------------------------------------------------------------
// CSR step 1 (both graphs fused): histogram of dst + per-edge rank.
// ---------------------------------------------------------------------------
__global__ __launch_bounds__(256) void hist_rank2_kernel(
    const int* __restrict__ d1, int E1, int* __restrict__ cnt1, int* __restrict__ rank1,
    const int* __restrict__ d2, int E2, int* __restrict__ cnt2, int* __restrict__ rank2) {
  int e = blockIdx.x * 256 + threadIdx.x;
  if (e < E1) {
    rank1[e] = atomicAdd(&cnt1[d1[e]], 1);
  } else {
    e -= E1;
    if (e < E2) rank2[e] = atomicAdd(&cnt2[d2[e]], 1);
  }
}

// ---------------------------------------------------------------------------
// CSR step 2a: per-1024-chunk exclusive scan -> ofs, chunk totals -> bsum.
// ---------------------------------------------------------------------------
__global__ __launch_bounds__(256) void scan_blk2_kernel(
    const int* __restrict__ cnt1, int n1, int* __restrict__ ofs1, int* __restrict__ bsum1, int nb1,
    const int* __restrict__ cnt2, int n2, int* __restrict__ ofs2, int* __restrict__ bsum2) {
  const int* cnt; int n; int* ofs; int* bsum; int lb;
  if ((int)blockIdx.x < nb1) { cnt = cnt1; n = n1; ofs = ofs1; bsum = bsum1; lb = blockIdx.x; }
  else                       { cnt = cnt2; n = n2; ofs = ofs2; bsum = bsum2; lb = blockIdx.x - nb1; }

  __shared__ int tsum[256];
  int t = threadIdx.x;
  int base = lb * 1024 + t * 4;
  int v0 = (base     < n) ? cnt[base]     : 0;
  int v1 = (base + 1 < n) ? cnt[base + 1] : 0;
  int v2 = (base + 2 < n) ? cnt[base + 2] : 0;
  int v3 = (base + 3 < n) ? cnt[base + 3] : 0;
  tsum[t] = v0 + v1 + v2 + v3;
  __syncthreads();
  for (int d = 1; d < 256; d <<= 1) {
    int x = (t >= d) ? tsum[t - d] : 0;
    __syncthreads();
    tsum[t] += x;
    __syncthreads();
  }
  int ex = (t == 0) ? 0 : tsum[t - 1];
  if (base     < n) ofs[base]     = ex;
  if (base + 1 < n) ofs[base + 1] = ex + v0;
  if (base + 2 < n) ofs[base + 2] = ex + v0 + v1;
  if (base + 3 < n) ofs[base + 3] = ex + v0 + v1 + v2;
  if (t == 255) bsum[lb] = tsum[255];
}

// ---------------------------------------------------------------------------
// CSR step 2b: wave-scan of chunk sums; grand totals -> ofs[n].
// ---------------------------------------------------------------------------
__global__ __launch_bounds__(128) void scan_bsum2_kernel(
    int* __restrict__ bsum1, int nb1, int* __restrict__ ofs1, int n1, int total1,
    int* __restrict__ bsum2, int nb2, int* __restrict__ ofs2, int n2, int total2) {
  int w = threadIdx.x >> 6;
  int lane = threadIdx.x & 63;
  int* bsum = w ? bsum2 : bsum1;
  int nb    = w ? nb2   : nb1;
  int orig = (lane < nb) ? bsum[lane] : 0;
  int v = orig;
  for (int d = 1; d < 64; d <<= 1) {
    int u = __shfl_up(v, d);
    if (lane >= d) v += u;
  }
  if (lane < nb) bsum[lane] = v - orig;   // exclusive
  if (lane == 0) {
    if (w) ofs2[n2] = total2; else ofs1[n1] = total1;
  }
}

// ---------------------------------------------------------------------------
// CSR step 2c: add chunk base offsets in place.
// ---------------------------------------------------------------------------
__global__ __launch_bounds__(256) void scan_add2_kernel(
    int* __restrict__ ofs1, int n1, const int* __restrict__ bsum1, int nblk1,
    int* __restrict__ ofs2, int n2, const int* __restrict__ bsum2) {
  int blk = blockIdx.x;
  int t = threadIdx.x;
  if (blk < nblk1) {
    int i = blk * 256 + t;
    if (i < n1) ofs1[i] += bsum1[i >> 10];
  } else {
    int i = (blk - nblk1) * 256 + t;
    if (i < n2) ofs2[i] += bsum2[i >> 10];
  }
}

// ---------------------------------------------------------------------------
// CSR step 3 (both graphs fused): scatter (src, w) into dst-sorted order.
// ---------------------------------------------------------------------------
__global__ __launch_bounds__(256) void scatter2_kernel(
    const int* __restrict__ s1, const int* __restrict__ d1, const float* __restrict__ w1,
    const int* __restrict__ rank1, const int* __restrict__ ofs1, int E1,
    unsigned long long* __restrict__ sorted1,
    const int* __restrict__ s2, const int* __restrict__ d2, const float* __restrict__ w2,
    const int* __restrict__ rank2, const int* __restrict__ ofs2, int E2,
    unsigned long long* __restrict__ sorted2) {
  int e = blockIdx.x * 256 + threadIdx.x;
  if (e < E1) {
    int pos = ofs1[d1[e]] + rank1[e];
    unsigned long long pk =
        (unsigned long long)(unsigned int)s1[e] |
        ((unsigned long long)__float_as_uint(w1[e]) << 32);
    __builtin_nontemporal_store(pk, sorted1 + pos);
  } else {
    e -= E1;
    if (e < E2) {
      int pos = ofs2[d2[e]] + rank2[e];
      unsigned long long pk =
          (unsigned long long)(unsigned int)s2[e] |
          ((unsigned long long)__float_as_uint(w2[e]) << 32);
      __builtin_nontemporal_store(pk, sorted2 + pos);
    }
  }
}

// ---------------------------------------------------------------------------
// Transpose W (128x128): WT[d][c] = W[c][d].
// ---------------------------------------------------------------------------
__global__ __launch_bounds__(256) void wt_kernel(
    const float* __restrict__ W, float* __restrict__ WT) {
  int idx = blockIdx.x * 256 + threadIdx.x;
  int c = idx >> 7;
  int d = idx & 127;
  WT[d * DD + c] = W[idx];
}

// ===========================================================================
// bf16 gather path
// ===========================================================================
// lane owns cols {2*lane, 2*lane+1} packed in one u32 (row = 64 u32 = 256B).
#define GATHER_B(P, VX, VY)                                                \
  {                                                                        \
    int s_ = (int)(unsigned int)(P);                                       \
    unsigned int v_ = (h_in + (size_t)s_ * 64)[lane];                      \
    float w_ = __uint_as_float((unsigned int)((P) >> 32));                 \
    VX += bf_lo(v_) * w_;                                                  \
    VY += bf_hi(v_) * w_;                                                  \
  }

// SpMM block 1: xb (bf16) -> h1b (bf16). One wave per dst row.
__global__ __launch_bounds__(256) void spmm_csr_bf16_kernel(
    const unsigned int* __restrict__ h_in,
    const int* __restrict__ ofs,
    const unsigned long long* __restrict__ sorted,
    unsigned int* __restrict__ h_out,
    int nrows) {
  int wave = (blockIdx.x * 256 + threadIdx.x) >> 6;
  int lane = threadIdx.x & 63;
  if (wave >= nrows) return;

  int lo = ofs[wave];
  int hi = ofs[wave + 1];

  float accx = 0.f, accy = 0.f;
  float ax1 = 0.f, ay1 = 0.f;
  int j = lo;
  for (; j + 8 <= hi; j += 8) {
    unsigned long long p0 = __builtin_nontemporal_load(sorted + j);
    unsigned long long p1 = __builtin_nontemporal_load(sorted + j + 1);
    unsigned long long p2 = __builtin_nontemporal_load(sorted + j + 2);
    unsigned long long p3 = __builtin_nontemporal_load(sorted + j + 3);
    unsigned long long p4 = __builtin_nontemporal_load(sorted + j + 4);
    unsigned long long p5 = __builtin_nontemporal_load(sorted + j + 5);
    unsigned long long p6 = __builtin_nontemporal_load(sorted + j + 6);
    unsigned long long p7 = __builtin_nontemporal_load(sorted + j + 7);
    GATHER_B(p0, accx, accy) GATHER_B(p1, ax1, ay1)
    GATHER_B(p2, accx, accy) GATHER_B(p3, ax1, ay1)
    GATHER_B(p4, accx, accy) GATHER_B(p5, ax1, ay1)
    GATHER_B(p6, accx, accy) GATHER_B(p7, ax1, ay1)
  }
  for (; j + 2 <= hi; j += 2) {
    unsigned long long p0 = __builtin_nontemporal_load(sorted + j);
    unsigned long long p1 = __builtin_nontemporal_load(sorted + j + 1);
    GATHER_B(p0, accx, accy) GATHER_B(p1, ax1, ay1)
  }
  if (j < hi) {
    unsigned long long p0 = __builtin_nontemporal_load(sorted + j);
    GATHER_B(p0, accx, accy)
  }

  (h_out + (size_t)wave * 64)[lane] = pack_bf2(accx + ax1, accy + ay1);
}

// SpMM block 2 (bf16 gather) + coalesced fp32 linear epilogue.
__global__ __launch_bounds__(256) void spmm_linear_bf16_kernel(
    const unsigned int* __restrict__ h_in,
    const int* __restrict__ ofs,
    const unsigned long long* __restrict__ sorted,
    const float* __restrict__ WT,
    const float* __restrict__ b,
    float* __restrict__ out,
    int nrows) {
  __shared__ float hrow[4][DD];
  int wid  = threadIdx.x >> 6;
  int lane = threadIdx.x & 63;
  int row  = blockIdx.x * 4 + wid;
  if (row >= nrows) return;

  int lo = ofs[row];
  int hi = ofs[row + 1];

  float accx = 0.f, accy = 0.f;
  float ax1 = 0.f, ay1 = 0.f;
  int j = lo;
  for (; j + 4 <= hi; j += 4) {
    unsigned long long p0 = __builtin_nontemporal_load(sorted + j);
    unsigned long long p1 = __builtin_nontemporal_load(sorted + j + 1);
    unsigned long long p2 = __builtin_nontemporal_load(sorted + j + 2);
    unsigned long long p3 = __builtin_nontemporal_load(sorted + j + 3);
    GATHER_B(p0, accx, accy) GATHER_B(p1, ax1, ay1)
    GATHER_B(p2, accx, accy) GATHER_B(p3, ax1, ay1)
  }
  for (; j < hi; ++j) {
    unsigned long long p0 = __builtin_nontemporal_load(sorted + j);
    GATHER_B(p0, accx, accy)
  }

  hrow[wid][2 * lane]     = accx + ax1;
  hrow[wid][2 * lane + 1] = accy + ay1;
  // wave-synchronous: same wave writes then reads hrow[wid]

  const float2* bp = reinterpret_cast<const float2*>(b);
  float2 bb = bp[lane];
  float a0 = bb.x;
  float a1 = bb.y;
  const float* hr = hrow[wid];
#pragma unroll 8
  for (int d = 0; d < DD; ++d) {
    float h = hr[d];  // LDS broadcast
    float2 w = *reinterpret_cast<const float2*>(WT + (size_t)d * DD + 2 * lane);
    a0 += h * w.x;
    a1 += h * w.y;
  }
  float2 o;
  o.x = a0;
  o.y = a1;
  reinterpret_cast<float2*>(out + (size_t)row * DD)[lane] = o;
}
#undef GATHER_B

// ===========================================================================
// fp32 gather path (fallback if workspace too small for bf16 buffers)
// ===========================================================================
#define GATHER(P, VX, VY)                                                        \
  {                                                                              \
    int s_ = (int)(unsigned int)(P);                                             \
    const float2* pr_ = reinterpret_cast<const float2*>(h_in + (size_t)s_ * DD); \
    float2 v_ = pr_[lane];                                                       \
    float w_ = __uint_as_float((unsigned int)((P) >> 32));                       \
    VX += v_.x * w_;                                                             \
    VY += v_.y * w_;                                                             \
  }

__global__ __launch_bounds__(256) void spmm_csr_kernel(
    const float* __restrict__ h_in,
    const int* __restrict__ ofs,
    const unsigned long long* __restrict__ sorted,
    float* __restrict__ h_out,
    int nrows) {
  int wave = (blockIdx.x * 256 + threadIdx.x) >> 6;
  int lane = threadIdx.x & 63;
  if (wave >= nrows) return;

  int lo = ofs[wave];
  int hi = ofs[wave + 1];

  float accx = 0.f, accy = 0.f;
  float ax1 = 0.f, ay1 = 0.f;
  int j = lo;
  for (; j + 8 <= hi; j += 8) {
    unsigned long long p0 = __builtin_nontemporal_load(sorted + j);
    unsigned long long p1 = __builtin_nontemporal_load(sorted + j + 1);
    unsigned long long p2 = __builtin_nontemporal_load(sorted + j + 2);
    unsigned long long p3 = __builtin_nontemporal_load(sorted + j + 3);
    unsigned long long p4 = __builtin_nontemporal_load(sorted + j + 4);
    unsigned long long p5 = __builtin_nontemporal_load(sorted + j + 5);
    unsigned long long p6 = __builtin_nontemporal_load(sorted + j + 6);
    unsigned long long p7 = __builtin_nontemporal_load(sorted + j + 7);
    GATHER(p0, accx, accy) GATHER(p1, ax1, ay1)
    GATHER(p2, accx, accy) GATHER(p3, ax1, ay1)
    GATHER(p4, accx, accy) GATHER(p5, ax1, ay1)
    GATHER(p6, accx, accy) GATHER(p7, ax1, ay1)
  }
  for (; j + 2 <= hi; j += 2) {
    unsigned long long p0 = __builtin_nontemporal_load(sorted + j);
    unsigned long long p1 = __builtin_nontemporal_load(sorted + j + 1);
    GATHER(p0, accx, accy) GATHER(p1, ax1, ay1)
  }
  if (j < hi) {
    unsigned long long p0 = __builtin_nontemporal_load(sorted + j);
    GATHER(p0, accx, accy)
  }

  float2 o;
  o.x = accx + ax1;
  o.y = accy + ay1;
  reinterpret_cast<float2*>(h_out + (size_t)wave * DD)[lane] = o;
}

__global__ __launch_bounds__(256) void spmm_linear_kernel(
    const float* __restrict__ h_in,
    const int* __restrict__ ofs,
    const unsigned long long* __restrict__ sorted,
    const float* __restrict__ WT,
    const float* __restrict__ b,
    float* __restrict__ out,
    int nrows) {
  __shared__ float hrow[4][DD];
  int wid  = threadIdx.x >> 6;
  int lane = threadIdx.x & 63;
  int row  = blockIdx.x * 4 + wid;
  if (row >= nrows) return;

  int lo = ofs[row];
  int hi = ofs[row + 1];

  float accx = 0.f, accy = 0.f;
  float ax1 = 0.f, ay1 = 0.f;
  int j = lo;
  for (; j + 4 <= hi; j += 4) {
    unsigned long long p0 = __builtin_nontemporal_load(sorted + j);
    unsigned long long p1 = __builtin_nontemporal_load(sorted + j + 1);
    unsigned long long p2 = __builtin_nontemporal_load(sorted + j + 2);
    unsigned long long p3 = __builtin_nontemporal_load(sorted + j + 3);
    GATHER(p0, accx, accy) GATHER(p1, ax1, ay1)
    GATHER(p2, accx, accy) GATHER(p3, ax1, ay1)
  }
  for (; j < hi; ++j) {
    unsigned long long p0 = __builtin_nontemporal_load(sorted + j);
    GATHER(p0, accx, accy)
  }

  hrow[wid][2 * lane]     = accx + ax1;
  hrow[wid][2 * lane + 1] = accy + ay1;

  const float2* bp = reinterpret_cast<const float2*>(b);
  float2 bb = bp[lane];
  float a0 = bb.x;
  float a1 = bb.y;
  const float* hr = hrow[wid];
#pragma unroll 8
  for (int d = 0; d < DD; ++d) {
    float h = hr[d];
    float2 w = *reinterpret_cast<const float2*>(WT + (size_t)d * DD + 2 * lane);
    a0 += h * w.x;
    a1 += h * w.y;
  }
  float2 o;
  o.x = a0;
  o.y = a1;
  reinterpret_cast<float2*>(out + (size_t)row * DD)[lane] = o;
}
#undef GATHER

static inline size_t align256(size_t x) { return (x + 255) & ~size_t(255); }

extern "C" void kernel_launch(void* const* d_in, const int* in_sizes, int n_in,
                              void* d_out, int out_size, void* d_ws, size_t ws_size,
                              hipStream_t stream) {
  const float* x   = (const float*)d_in[0];
  const float* ew1 = (const float*)d_in[1];
  const float* ew2 = (const float*)d_in[2];
  const float* W   = (const float*)d_in[3];
  const float* b   = (const float*)d_in[4];
  const int* e1_src = (const int*)d_in[5];
  const int* e1_dst = (const int*)d_in[6];
  const int* e2_src = (const int*)d_in[7];
  const int* e2_dst = (const int*)d_in[8];
  float* out = (float*)d_out;

  int E1 = in_sizes[1];
  int E2 = in_sizes[2];

  int nb1 = (cN1 + 1023) / 1024;  // 49
  int nb2 = (cN2 + 1023) / 1024;  // 10

  // size of the bf16 path's workspace
  size_t need_bf16 =
      align256((size_t)cN0 * DD * 2) +        // xb
      align256((size_t)cN1 * DD * 2) +        // h1b
      align256((size_t)DD * DD * 4) +         // WT
      align256((size_t)(cN1 + cN2) * 4) +     // cnt
      align256((size_t)(cN1 + 1) * 4) +
      align256((size_t)(cN2 + 1) * 4) +
      2 * align256(64 * 4) +
      align256((size_t)E1 * 4) + align256((size_t)E2 * 4) +   // rank
      align256((size_t)E1 * 8) + align256((size_t)E2 * 8);    // sorted

  bool use_bf16 = ws_size >= need_bf16;

  char* p = (char*)d_ws;
  unsigned int* xb = nullptr;
  unsigned int* h1b = nullptr;
  float* h1f = nullptr;
  if (use_bf16) {
    xb  = (unsigned int*)p;  p += align256((size_t)cN0 * DD * 2);
    h1b = (unsigned int*)p;  p += align256((size_t)cN1 * DD * 2);
  } else {
    h1f = (float*)p;         p += align256((size_t)cN1 * DD * 4);
  }
  float* WT = (float*)p;     p += align256((size_t)DD * DD * 4);
  int* cnt1 = (int*)p;
  int* cnt2 = cnt1 + cN1;    p += align256((size_t)(cN1 + cN2) * 4);
  int* ofs1 = (int*)p;       p += align256((size_t)(cN1 + 1) * 4);
  int* ofs2 = (int*)p;       p += align256((size_t)(cN2 + 1) * 4);
  int* bsum1 = (int*)p;      p += align256(64 * 4);
  int* bsum2 = (int*)p;      p += align256(64 * 4);
  int* rank1 = (int*)p;      p += align256((size_t)E1 * 4);
  int* rank2 = (int*)p;      p += align256((size_t)E2 * 4);
  unsigned long long* sorted1 = (unsigned long long*)p;  p += align256((size_t)E1 * 8);
  unsigned long long* sorted2 = (unsigned long long*)p;  p += align256((size_t)E2 * 8);

  // 1) zero both histograms
  hipMemsetAsync(cnt1, 0, (size_t)(cN1 + cN2) * 4, stream);

  // 2) transpose W; convert x to bf16 (bf16 path)
  wt_kernel<<<64, 256, 0, stream>>>(W, WT);
  if (use_bf16) {
    long long n8 = (long long)cN0 * DD / 8;
    cvt_bf16_kernel<<<(int)((n8 + 255) / 256), 256, 0, stream>>>(x, xb, n8);
  }

  // 3) fused histogram + rank
  {
    int total = E1 + E2;
    hist_rank2_kernel<<<(total + 255) / 256, 256, 0, stream>>>(
        e1_dst, E1, cnt1, rank1, e2_dst, E2, cnt2, rank2);
  }

  // 4) parallel scan
  scan_blk2_kernel<<<nb1 + nb2, 256, 0, stream>>>(cnt1, cN1, ofs1, bsum1, nb1,
                                                  cnt2, cN2, ofs2, bsum2);
  scan_bsum2_kernel<<<1, 128, 0, stream>>>(bsum1, nb1, ofs1, cN1, E1,
                                           bsum2, nb2, ofs2, cN2, E2);
  {
    int nblk1 = (cN1 + 255) / 256;
    int nblk2 = (cN2 + 255) / 256;
    scan_add2_kernel<<<nblk1 + nblk2, 256, 0, stream>>>(ofs1, cN1, bsum1, nblk1,
                                                        ofs2, cN2, bsum2);
  }

  // 5) fused scatter
  {
    int total = E1 + E2;
    scatter2_kernel<<<(total + 255) / 256, 256, 0, stream>>>(
        e1_src, e1_dst, ew1, rank1, ofs1, E1, sorted1,
        e2_src, e2_dst, ew2, rank2, ofs2, E2, sorted2);
  }

  int nrows = out_size / DD;  // N2

  if (use_bf16) {
    // 6) SpMM block 1: xb -> h1b (bf16 gather, bf16 out)
    spmm_csr_bf16_kernel<<<(cN1 + 3) / 4, 256, 0, stream>>>(xb, ofs1, sorted1, h1b, cN1);
    // 7) SpMM block 2 + linear: h1b -> out
    spmm_linear_bf16_kernel<<<(nrows + 3) / 4, 256, 0, stream>>>(
        h1b, ofs2, sorted2, WT, b, out, nrows);
  } else {
    spmm_csr_kernel<<<(cN1 + 3) / 4, 256, 0, stream>>>(x, ofs1, sorted1, h1f, cN1);
    spmm_linear_kernel<<<(nrows + 3) / 4, 256, 0, stream>>>(
        h1f, ofs2, sorted2, WT, b, out, nrows);
  }
}